// Round 5
// baseline (2310.296 us; speedup 1.0000x reference)
//
#include <hip/hip_runtime.h>
#include <math.h>

// Problem constants (match reference)
#define NN   50000
#define FF   128
#define RBFD 20
#define EE   800000
#define C3F  384
#define TE   32      // phi tile / fallback tile
#define TN   16      // edges per chunk in node kernel (MFMA M=16)
#define TEH  64      // edges per block in h_kernel
#define KC   16      // k-chunk staged in LDS (fallback kernels)
#define HP   36      // padded stride for fallback LDS tiles

typedef __attribute__((ext_vector_type(8))) short bhalf8;   // 8 bf16 (4 VGPRs)
typedef __attribute__((ext_vector_type(4))) float floatx4;  // MFMA acc

__device__ __forceinline__ float softplus_m_log2(float x) {
  float t = __expf(-fabsf(x));
  return fmaxf(x, 0.0f) + __logf(1.0f + t) - 0.6931471805599453f;
}

__device__ __forceinline__ short f2bf(float x) {
  unsigned u = __float_as_uint(x);
  u += 0x7fffu + ((u >> 16) & 1u);   // round-to-nearest-even
  return (short)(u >> 16);
}
__device__ __forceinline__ float bflo(unsigned u) { return __uint_as_float(u << 16); }
__device__ __forceinline__ float bfhi(unsigned u) { return __uint_as_float(u & 0xffff0000u); }

// packed feature index: pairs (f, f+16) adjacent within each 32-feature group
__device__ __forceinline__ int pkf(int f) {
  return ((f >> 5) << 5) | ((f & 15) << 1) | ((f >> 4) & 1);
}

// ==================== CSR build ====================
__global__ void hist_kernel(const int* __restrict__ edge_index, int* __restrict__ cursor) {
  int e = blockIdx.x * 256 + threadIdx.x;
  if (e < EE) atomicAdd(&cursor[edge_index[e]], 1);
}

// single-block scan, each thread owns 49 consecutive elements
__global__ void scan_kernel(int* __restrict__ cursor, int* __restrict__ row_start) {
  __shared__ int sums[1024];
  const int tid = threadIdx.x;
  const int CH = 49;                 // 49*1024 >= NN
  int base = tid * CH;
  int vals[CH];
  int local = 0;
#pragma unroll
  for (int j = 0; j < CH; ++j) {
    int i = base + j;
    int x = (i < NN) ? cursor[i] : 0;
    vals[j] = x;
    local += x;
  }
  sums[tid] = local;
  __syncthreads();
  for (int off = 1; off < 1024; off <<= 1) {
    int v2 = (tid >= off) ? sums[tid - off] : 0;
    __syncthreads();
    sums[tid] += v2;
    __syncthreads();
  }
  int excl = sums[tid] - local;
#pragma unroll
  for (int j = 0; j < CH; ++j) {
    int i = base + j;
    if (i < NN) { row_start[i] = excl; cursor[i] = excl; }
    excl += vals[j];
  }
  if (tid == 1023) row_start[NN] = excl;
}

__global__ void fill_kernel(const int* __restrict__ edge_index, int* __restrict__ cursor,
                            int* __restrict__ perm) {
  int e = blockIdx.x * 256 + threadIdx.x;
  if (e < EE) {
    int s = edge_index[e];
    int pos = atomicAdd(&cursor[s], 1);
    perm[pos] = e;
  }
}

// fill that also materializes dst in permuted order (kills one gather hop)
__global__ void fill2_kernel(const int* __restrict__ edge_index, int* __restrict__ cursor,
                             int* __restrict__ perm, int* __restrict__ dst_perm) {
  int e = blockIdx.x * 256 + threadIdx.x;
  if (e < EE) {
    int s = edge_index[e];
    int d = edge_index[EE + e];
    int pos = atomicAdd(&cursor[s], 1);
    perm[pos] = e;
    dst_perm[pos] = d;
  }
}

// ==================== weight conversion ====================
// f2t[n][k]   = bf16(f2_W[k][n])          (row layout, fallback path)
// f2frag      = fragment-order: for 16-col group c16 (24) x ks (4):
//               [((c16*4+ks)*64 + lane)*8 + j8] = bf16(f2_W[k][n]),
//               n = c16*16 + (lane&15), k = ks*32 + (lane>>4)*8 + j8.
//               -> node2's B fragment load is one coalesced dwordx4 per wave.
// f1t[f][40]
__global__ void conv_kernel(const float* __restrict__ f1_W, const float* __restrict__ f2_W,
                            short* __restrict__ f1t, short* __restrict__ f2t,
                            short* __restrict__ f2frag) {
  int i = blockIdx.x * 256 + threadIdx.x;
  if (i < C3F * FF) {
    int n = i >> 7, k = i & 127;
    f2t[i] = f2bf(f2_W[(size_t)k * C3F + n]);
    if (f2frag) {
      int j8 = i & 7, lane = (i >> 3) & 63, ks = (i >> 9) & 3, c16 = i >> 11;
      int l = lane & 15, q = lane >> 4;
      int nf = c16 * 16 + l;
      int kf = ks * 32 + q * 8 + j8;
      f2frag[i] = f2bf(f2_W[(size_t)kf * C3F + nf]);
    }
  }
  if (i < FF * 40) {
    int f = i / 40, k = i - f * 40;
    f1t[i] = (k < RBFD) ? f2bf(f1_W[(size_t)k * FF + f]) : (short)0;
  }
}

// ==================== v -> packed bf16 (4B-word stores, coalesced)
// layout: v_b16[n][g*96 + l*6 + c*2 + h] shorts; one thread packs the (h=0,h=1) pair
__global__ void vconv_kernel(const float* __restrict__ v, short* __restrict__ v_b16) {
  int i = blockIdx.x * 256 + threadIdx.x;
  if (i < NN * 192) {
    int n = i / 192;
    int rem = i - n * 192;
    int g = rem / 48;
    int w = rem - g * 48;
    int l = w / 3;
    int c = w - l * 3;
    float v0 = v[((size_t)n * FF + g * 32 + l) * 3 + c];        // h=0 -> f=g*32+l
    float v1 = v[((size_t)n * FF + g * 32 + 16 + l) * 3 + c];   // h=1 -> f=g*32+16+l
    unsigned word = (unsigned)(unsigned short)f2bf(v0) |
                    ((unsigned)(unsigned short)f2bf(v1) << 16);
    ((unsigned*)v_b16)[(size_t)n * 192 + rem] = word;
  }
}

// ==================== per-node phi GEMM -> packed bf16 phi_b16[n][256]
// [0:128] = phi_s+b (pkf layout), [128:256] = phi_r+b
__global__ __launch_bounds__(256, 3)
void phi_kernel(const float* __restrict__ s, const float* __restrict__ phi_W,
                const float* __restrict__ phi_b, short* __restrict__ phi_b16) {
  __shared__ float s_t[FF * HP];
  __shared__ __align__(16) float w_ch[KC * 256];   // reused as output staging
  const int tid = threadIdx.x;
  const int r0 = blockIdx.x * TE;

  for (int i = tid; i < TE * (FF / 4); i += 256) {
    int row = i >> 5, k4 = i & 31;
    int rg = r0 + row;
    float4 sv = make_float4(0.f, 0.f, 0.f, 0.f);
    if (rg < NN) sv = *(const float4*)(s + (size_t)rg * FF + k4 * 4);
    s_t[(k4 * 4 + 0) * HP + row] = sv.x;
    s_t[(k4 * 4 + 1) * HP + row] = sv.y;
    s_t[(k4 * 4 + 2) * HP + row] = sv.z;
    s_t[(k4 * 4 + 3) * HP + row] = sv.w;
  }
  const int tc = tid & 31, tr = tid >> 5;
  float acc[2][4][4];
#pragma unroll
  for (int g = 0; g < 2; ++g)
#pragma unroll
    for (int a = 0; a < 4; ++a)
#pragma unroll
      for (int b = 0; b < 4; ++b) acc[g][a][b] = 0.f;

  for (int kc = 0; kc < FF / KC; ++kc) {
    __syncthreads();
    for (int i = tid; i < KC * 64; i += 256) {
      int k = i >> 6, j4 = i & 63;
      int j = j4 * 4;
      int col = (j < 128) ? j : (j + 128);
      *(float4*)&w_ch[k * 256 + j] =
          *(const float4*)(phi_W + (size_t)(kc * KC + k) * C3F + col);
    }
    __syncthreads();
#pragma unroll
    for (int k = 0; k < KC; ++k) {
      float4 s4 = *(const float4*)&s_t[(kc * KC + k) * HP + tr * 4];
      float sr[4] = {s4.x, s4.y, s4.z, s4.w};
#pragma unroll
      for (int g = 0; g < 2; ++g) {
        float4 w4 = *(const float4*)&w_ch[k * 256 + g * 128 + tc * 4];
        float wr[4] = {w4.x, w4.y, w4.z, w4.w};
#pragma unroll
        for (int er = 0; er < 4; ++er)
#pragma unroll
          for (int fc = 0; fc < 4; ++fc) acc[g][er][fc] += sr[er] * wr[fc];
      }
    }
  }
  const int f0 = tc * 4;
  float4 b0 = *(const float4*)(phi_b + f0);
  float4 b2 = *(const float4*)(phi_b + 256 + f0);
  float bb[2][4] = {{b0.x, b0.y, b0.z, b0.w}, {b2.x, b2.y, b2.z, b2.w}};

  __syncthreads();                       // done reading w_ch as weights
  short* ob = (short*)w_ch;              // [32 rows][256] packed bf16
#pragma unroll
  for (int er = 0; er < 4; ++er) {
    int row = tr * 4 + er;
#pragma unroll
    for (int g = 0; g < 2; ++g) {
#pragma unroll
      for (int fc = 0; fc < 4; ++fc) {
        int f = f0 + fc;
        ob[row * 256 + g * 128 + pkf(f)] = f2bf(acc[g][er][fc] + bb[g][fc]);
      }
    }
  }
  __syncthreads();
  // coalesced store: 32 rows x 512B = 1024 int4
  for (int i = tid; i < 1024; i += 256) {
    int row = i >> 5;
    int rg = r0 + row;
    if (rg < NN)
      ((int4*)(phi_b16 + (size_t)rg * 256))[i & 31] = ((const int4*)ob)[i];
  }
}

// ==================== edge-parallel h precompute in permuted order ====================
// h_perm[i][f] = bf16( softplus(e_ij[perm[i]] @ f1_W + f1_b) - log2 ), plain f order
// ALSO writes rhp (r_hat in permuted order) -- folded-in former rperm_kernel.
__global__ __launch_bounds__(256, 6)
void h_kernel(const float* __restrict__ e_ij, const float* __restrict__ f1_b,
              const float* __restrict__ r_hat,
              const int* __restrict__ perm, const short* __restrict__ f1t_g,
              short* __restrict__ h_perm, float* __restrict__ rhp) {
  __shared__ __align__(16) short e_pad2[TEH * 40];  // 5 KB
  __shared__ int pl[TEH];
  const int tid = threadIdx.x;
  const int wid = tid >> 6;
  const int lane = tid & 63;
  const int l = lane & 15;
  const int q = lane >> 4;
  const int e0 = blockIdx.x * TEH;

  if (tid < TEH) {
    int idx = e0 + tid;
    pl[tid] = (idx < EE) ? perm[idx] : -1;
  }
  __syncthreads();
  // r_hat permute (gathered read, coalesced write)
  if (tid < TEH * 3) {
    int le = tid / 3, c = tid - le * 3;
    int idx = e0 + le;
    if (idx < EE) {
      int eid = pl[le];
      rhp[(size_t)idx * 3 + c] = (eid >= 0) ? r_hat[(size_t)eid * 3 + c] : 0.f;
    }
  }
  for (int i = tid; i < TEH * 32; i += 256) {
    int e = i >> 5, k = i & 31;
    int eid = pl[e];
    float val = (eid >= 0 && k < RBFD) ? e_ij[(size_t)eid * RBFD + k] : 0.f;
    e_pad2[e * 40 + k] = f2bf(val);
  }
  const int f0 = wid * 32 + l;
  const int f1 = f0 + 16;
  const bhalf8 b1f0 = *(const bhalf8*)(f1t_g + f0 * 40 + q * 8);
  const bhalf8 b1f1 = *(const bhalf8*)(f1t_g + f1 * 40 + q * 8);
  const float f1b0 = f1_b[f0], f1b1 = f1_b[f1];
  __syncthreads();

#pragma unroll
  for (int rt = 0; rt < 4; ++rt) {
    bhalf8 a = *(const bhalf8*)(&e_pad2[(rt * 16 + l) * 40 + q * 8]);
    floatx4 h0 = {0.f, 0.f, 0.f, 0.f}, h1 = {0.f, 0.f, 0.f, 0.f};
    h0 = __builtin_amdgcn_mfma_f32_16x16x32_bf16(a, b1f0, h0, 0, 0, 0);
    h1 = __builtin_amdgcn_mfma_f32_16x16x32_bf16(a, b1f1, h1, 0, 0, 0);
#pragma unroll
    for (int r = 0; r < 4; ++r) {
      int idx = e0 + rt * 16 + q * 4 + r;
      if (idx < EE) {
        h_perm[(size_t)idx * FF + f0] = f2bf(softplus_m_log2(h0[r] + f1b0));
        h_perm[(size_t)idx * FF + f1] = f2bf(softplus_m_log2(h1[r] + f1b1));
      }
    }
  }
}

// ==================== barrier-free, LDS-free node kernel (persistent, B streamed) ======
// Round-4 lesson: gfx950 unified VGPR/AGPR file -> __launch_bounds__ budget is
// TOTAL regs = 512/waves_per_EU; the persistent Bfr[6][4] (96 regs) put the
// footprint at ~170, so any bound >3 spilled. Fix: stream B fragments from a
// fragment-ordered, L2-resident f2frag buffer (one coalesced dwordx4 per
// fragment, dead after use). Footprint ~110 -> fits (256,4) = 128, no spill,
// 50% occupancy. Occupancy->BW law (33%->2.0, 45%->3.6 TB/s) says ~1.5x.
__global__ __launch_bounds__(256, 4)
void node2_kernel(const short* __restrict__ v_b16, const float* __restrict__ rhp,
                  const float* __restrict__ f2_b,
                  const int* __restrict__ row_start, const int* __restrict__ dst_perm,
                  const short* __restrict__ phi_b16, const short* __restrict__ h_perm,
                  const short* __restrict__ f2frag,
                  float* __restrict__ out_s, float* __restrict__ out_v) {
  const int tid = threadIdx.x;
  const int wid = tid >> 6;
  const int lane = tid & 63;
  const int l = lane & 15;
  const int q = lane >> 4;
  const int f0 = wid * 32 + l;
  const int f1 = f0 + 16;

  const float bs0 = f2_b[f0],        bs1 = f2_b[f1];
  const float bv0 = f2_b[FF + f0],   bv1 = f2_b[FF + f1];
  const float br0 = f2_b[2*FF + f0], br1 = f2_b[2*FF + f1];

  // per-thread base into fragment-ordered f2: fragment (c16, ks) lives at
  // (c16*4 + ks)*512 + lane*8 shorts; c16 = g*8 + wid*2 + hh.
  const short* fb = f2frag + (size_t)(wid * 2) * 4 * 512 + lane * 8;
  // per-(j,ks) short offsets: g*16384 + hh*2048 + ks*512 (compile-time in loop)

  for (int n = blockIdx.x; n < NN; n += gridDim.x) {
    const int rs = row_start[n];
    const int deg = row_start[n + 1] - rs;

    float dsA[2] = {0.f, 0.f};
    float dvA[2][3] = {{0.f, 0.f, 0.f}, {0.f, 0.f, 0.f}};

    // dst prefetch for the first chunk
    int dgN[4];
#pragma unroll
    for (int r = 0; r < 4; ++r)
      dgN[r] = dst_perm[min(rs + q * 4 + r, EE - 1)];

    for (int c0 = 0; c0 < deg; c0 += TN) {
      const int cnt = min(TN, deg - c0);
      const int base = rs + c0;

      const int dg0 = dgN[0], dg1 = dgN[1], dg2 = dgN[2], dg3 = dgN[3];
      const int dg[4] = {dg0, dg1, dg2, dg3};

      // ---- issue phi/v gathers EARLY so they fly under the MFMA block
      unsigned psu[4], pru[4], vu0[4], vu1[4], vu2[4];
#pragma unroll
      for (int r = 0; r < 4; ++r) {
        const short* pb = phi_b16 + (size_t)dg[r] * 256 + wid * 32 + l * 2;
        psu[r] = *(const unsigned*)pb;
        pru[r] = *(const unsigned*)(pb + 128);
        const short* vb = v_b16 + (size_t)dg[r] * 384 + wid * 96 + l * 6;
        vu0[r] = ((const unsigned*)vb)[0];
        vu1[r] = ((const unsigned*)vb)[1];
        vu2[r] = ((const unsigned*)vb)[2];
      }

      // ---- prefetch NEXT chunk's dst (independent; overlaps with MFMAs below)
#pragma unroll
      for (int r = 0; r < 4; ++r)
        dgN[r] = dst_perm[min(base + TN + q * 4 + r, EE - 1)];

      // ---- filt-GEMM: K=128, A from h_perm (contiguous rows), B streamed from
      //      L2-resident f2frag (coalesced dwordx4, used once -> no reg pressure)
      const int hrow = min(base + l, EE - 1);
      const short* hp = h_perm + (size_t)hrow * FF + q * 8;
      floatx4 acc[6];
#pragma unroll
      for (int j = 0; j < 6; ++j) acc[j] = (floatx4){0.f, 0.f, 0.f, 0.f};
#pragma unroll
      for (int ks = 0; ks < 4; ++ks) {
        bhalf8 a = *(const bhalf8*)(hp + ks * 32);
#pragma unroll
        for (int j = 0; j < 6; ++j) {
          const int g = j >> 1, hh = j & 1;
          bhalf8 b = *(const bhalf8*)(fb + g * 16384 + hh * 2048 + ks * 512);
          acc[j] = __builtin_amdgcn_mfma_f32_16x16x32_bf16(a, b, acc[j], 0, 0, 0);
        }
      }

      // ---- epilogue: branchless masked accumulate (gathers already in registers)
#pragma unroll
      for (int r = 0; r < 4; ++r) {
        int e = q * 4 + r;
        float valid = (e < cnt) ? 1.0f : 0.0f;
        float Ws0 = (acc[0][r] + bs0) * valid, Ws1 = (acc[1][r] + bs1) * valid;
        float Wv0 = (acc[2][r] + bv0) * valid, Wv1 = (acc[3][r] + bv1) * valid;
        float Wr0 = (acc[4][r] + br0) * valid, Wr1 = (acc[5][r] + br1) * valid;

        float ps0 = bflo(psu[r]), ps1 = bfhi(psu[r]);
        float pr0 = bflo(pru[r]), pr1 = bfhi(pru[r]);
        float v00 = bflo(vu0[r]), v10 = bfhi(vu0[r]);
        float v01 = bflo(vu1[r]), v11 = bfhi(vu1[r]);
        float v02 = bflo(vu2[r]), v12 = bfhi(vu2[r]);

        int ridx = min(base + e, EE - 1);
        const float* rp = rhp + (size_t)ridx * 3;
        float rh0 = rp[0], rh1 = rp[1], rh2 = rp[2];

        dsA[0] += Ws0 * ps0;
        dsA[1] += Ws1 * ps1;
        float w0 = Wr0 * pr0, w1 = Wr1 * pr1;
        dvA[0][0] += Wv0 * v00 + w0 * rh0;
        dvA[0][1] += Wv0 * v01 + w0 * rh1;
        dvA[0][2] += Wv0 * v02 + w0 * rh2;
        dvA[1][0] += Wv1 * v10 + w1 * rh0;
        dvA[1][1] += Wv1 * v11 + w1 * rh1;
        dvA[1][2] += Wv1 * v12 + w1 * rh2;
      }
    }

    // quad reduction (within wave)
#pragma unroll
    for (int a = 0; a < 2; ++a) {
      dsA[a] += __shfl_xor(dsA[a], 16);
      dsA[a] += __shfl_xor(dsA[a], 32);
#pragma unroll
      for (int c = 0; c < 3; ++c) {
        dvA[a][c] += __shfl_xor(dvA[a][c], 16);
        dvA[a][c] += __shfl_xor(dvA[a][c], 32);
      }
    }

    // direct stores from q==0 lanes (no LDS staging, no barriers)
    if (q == 0) {
      out_s[(size_t)n * FF + f0] = dsA[0];
      out_s[(size_t)n * FF + f1] = dsA[1];
#pragma unroll
      for (int c = 0; c < 3; ++c) {
        out_v[((size_t)n * FF + f0) * 3 + c] = dvA[0][c];
        out_v[((size_t)n * FF + f1) * 3 + c] = dvA[1][c];
      }
    }
  }
}

// ==================== OLD node-centric MFMA kernel (fallback tier) ====================
template <bool VB16>
__global__ __launch_bounds__(256, 3)
void node_mfma_kernel(const float* __restrict__ vf32, const short* __restrict__ v_b16,
                      const float* __restrict__ e_ij, const float* __restrict__ r_hat,
                      const float* __restrict__ f1_b, const float* __restrict__ f2_b,
                      const int* __restrict__ edge_index,
                      const int* __restrict__ row_start, const int* __restrict__ perm,
                      const short* __restrict__ phi_b16,
                      const short* __restrict__ f1t_g, const short* __restrict__ f2t_g,
                      float* __restrict__ out_s, float* __restrict__ out_v) {
  __shared__ __align__(16) short f1t_l[FF * 40];   // 10 KB
  __shared__ __align__(16) short e_pad[TN * 40];   // 1.25 KB
  __shared__ __align__(16) short h_buf[TN * 136];  // 4.25 KB; reused as f32 out staging
  __shared__ float rh_l[TN * 3];
  __shared__ int el[TN], dl[TN];

  const int tid = threadIdx.x;
  const int wid = tid >> 6;
  const int lane = tid & 63;
  const int l = lane & 15;
  const int q = lane >> 4;

  for (int i = tid; i < FF * 40 / 2; i += 256)
    ((int*)f1t_l)[i] = ((const int*)f1t_g)[i];

  const int f0 = wid * 32 + l;
  const int f1 = f0 + 16;

  const float f1b0 = f1_b[f0], f1b1 = f1_b[f1];
  const float bs0 = f2_b[f0],        bs1 = f2_b[f1];
  const float bv0 = f2_b[FF + f0],   bv1 = f2_b[FF + f1];
  const float br0 = f2_b[2*FF + f0], br1 = f2_b[2*FF + f1];

  bhalf8 Bfr[6][4];
#pragma unroll
  for (int j = 0; j < 6; ++j) {
    int g = j >> 1, hh = j & 1;
    int nc = g * 128 + wid * 32 + hh * 16 + l;
#pragma unroll
    for (int ks = 0; ks < 4; ++ks)
      Bfr[j][ks] = *(const bhalf8*)(f2t_g + (size_t)nc * FF + ks * 32 + q * 8);
  }

  __syncthreads();
  const bhalf8 b1f0 = *(const bhalf8*)(&f1t_l[f0 * 40 + q * 8]);
  const bhalf8 b1f1 = *(const bhalf8*)(&f1t_l[f1 * 40 + q * 8]);

  for (int n = blockIdx.x; n < NN; n += gridDim.x) {
    const int rs = row_start[n];
    const int deg = row_start[n + 1] - rs;

    float dsA[2] = {0.f, 0.f};
    float dvA[2][3] = {{0.f, 0.f, 0.f}, {0.f, 0.f, 0.f}};

    for (int c0 = 0; c0 < deg; c0 += TN) {
      const int cnt = min(TN, deg - c0);
      __syncthreads();

      if (tid < TN) {
        int idx = c0 + tid;
        int eid = (idx < deg) ? perm[rs + idx] : -1;
        el[tid] = eid;
        dl[tid] = (eid >= 0) ? edge_index[EE + eid] : 0;
        if (eid >= 0) {
          rh_l[tid * 3 + 0] = r_hat[(size_t)eid * 3 + 0];
          rh_l[tid * 3 + 1] = r_hat[(size_t)eid * 3 + 1];
          rh_l[tid * 3 + 2] = r_hat[(size_t)eid * 3 + 2];
        } else {
          rh_l[tid * 3 + 0] = 0.f; rh_l[tid * 3 + 1] = 0.f; rh_l[tid * 3 + 2] = 0.f;
        }
      }
      __syncthreads();
      for (int i = tid; i < TN * 32; i += 256) {
        int e = i >> 5, k = i & 31;
        int eid = el[e];
        float val = (eid >= 0 && k < RBFD) ? e_ij[(size_t)eid * RBFD + k] : 0.f;
        e_pad[e * 40 + k] = f2bf(val);
      }
      __syncthreads();

      {
        bhalf8 a = *(const bhalf8*)(&e_pad[l * 40 + q * 8]);
        floatx4 h0 = {0.f, 0.f, 0.f, 0.f}, h1 = {0.f, 0.f, 0.f, 0.f};
        h0 = __builtin_amdgcn_mfma_f32_16x16x32_bf16(a, b1f0, h0, 0, 0, 0);
        h1 = __builtin_amdgcn_mfma_f32_16x16x32_bf16(a, b1f1, h1, 0, 0, 0);
#pragma unroll
        for (int r = 0; r < 4; ++r) {
          int e = q * 4 + r;
          h_buf[e * 136 + f0] = f2bf(softplus_m_log2(h0[r] + f1b0));
          h_buf[e * 136 + f1] = f2bf(softplus_m_log2(h1[r] + f1b1));
        }
      }
      __syncthreads();

      floatx4 acc[6];
#pragma unroll
      for (int j = 0; j < 6; ++j) acc[j] = (floatx4){0.f, 0.f, 0.f, 0.f};
#pragma unroll
      for (int ks = 0; ks < 4; ++ks) {
        bhalf8 a = *(const bhalf8*)(&h_buf[l * 136 + ks * 32 + q * 8]);
#pragma unroll
        for (int j = 0; j < 6; ++j)
          acc[j] = __builtin_amdgcn_mfma_f32_16x16x32_bf16(a, Bfr[j][ks], acc[j], 0, 0, 0);
      }

#pragma unroll
      for (int r = 0; r < 4; ++r) {
        int e = q * 4 + r;
        int dg = dl[e];
        float valid = (e < cnt) ? 1.0f : 0.0f;
        float Ws0 = (acc[0][r] + bs0) * valid, Ws1 = (acc[1][r] + bs1) * valid;
        float Wv0 = (acc[2][r] + bv0) * valid, Wv1 = (acc[3][r] + bv1) * valid;
        float Wr0 = (acc[4][r] + br0) * valid, Wr1 = (acc[5][r] + br1) * valid;

        const short* pb = phi_b16 + (size_t)dg * 256 + wid * 32 + l * 2;
        unsigned psu = *(const unsigned*)pb;
        unsigned pru = *(const unsigned*)(pb + 128);
        float ps0 = bflo(psu), ps1 = bfhi(psu);
        float pr0 = bflo(pru), pr1 = bfhi(pru);

        float v00, v01, v02, v10, v11, v12;
        if constexpr (VB16) {
          const short* vb = v_b16 + (size_t)dg * 384 + wid * 96 + l * 6;
          unsigned u0 = ((const unsigned*)vb)[0];
          unsigned u1 = ((const unsigned*)vb)[1];
          unsigned u2 = ((const unsigned*)vb)[2];
          v00 = bflo(u0); v10 = bfhi(u0);
          v01 = bflo(u1); v11 = bfhi(u1);
          v02 = bflo(u2); v12 = bfhi(u2);
        } else {
          const float* vp0 = vf32 + ((size_t)dg * FF + f0) * 3;
          const float* vp1 = vf32 + ((size_t)dg * FF + f1) * 3;
          v00 = vp0[0]; v01 = vp0[1]; v02 = vp0[2];
          v10 = vp1[0]; v11 = vp1[1]; v12 = vp1[2];
        }
        float rh0 = rh_l[e * 3 + 0], rh1 = rh_l[e * 3 + 1], rh2 = rh_l[e * 3 + 2];
        dsA[0] += Ws0 * ps0;
        dsA[1] += Ws1 * ps1;
        float w0 = Wr0 * pr0, w1 = Wr1 * pr1;
        dvA[0][0] += Wv0 * v00 + w0 * rh0;
        dvA[0][1] += Wv0 * v01 + w0 * rh1;
        dvA[0][2] += Wv0 * v02 + w0 * rh2;
        dvA[1][0] += Wv1 * v10 + w1 * rh0;
        dvA[1][1] += Wv1 * v11 + w1 * rh1;
        dvA[1][2] += Wv1 * v12 + w1 * rh2;
      }
    }

#pragma unroll
    for (int a = 0; a < 2; ++a) {
      dsA[a] += __shfl_xor(dsA[a], 16);
      dsA[a] += __shfl_xor(dsA[a], 32);
#pragma unroll
      for (int c = 0; c < 3; ++c) {
        dvA[a][c] += __shfl_xor(dvA[a][c], 16);
        dvA[a][c] += __shfl_xor(dvA[a][c], 32);
      }
    }

    __syncthreads();
    float* ob = (float*)h_buf;
    if (q == 0) {
      ob[f0] = dsA[0];
      ob[f1] = dsA[1];
#pragma unroll
      for (int c = 0; c < 3; ++c) {
        ob[128 + f0 * 3 + c] = dvA[0][c];
        ob[128 + f1 * 3 + c] = dvA[1][c];
      }
    }
    __syncthreads();
    if (tid < 32)
      ((float4*)(out_s + (size_t)n * FF))[tid] = ((const float4*)ob)[tid];
    else if (tid < 128)
      ((float4*)(out_v + (size_t)n * C3F))[tid - 32] = ((const float4*)ob)[tid];
  }
}

// ==================== fallback: edge-parallel, inline phi, atomics (no ws) ============
__global__ __launch_bounds__(256, 2)
void edge_kernel(const float* __restrict__ sfeat, const float* __restrict__ v,
                 const float* __restrict__ e_ij, const float* __restrict__ r_hat,
                 const float* __restrict__ phi_W, const float* __restrict__ phi_b,
                 const float* __restrict__ f1_W, const float* __restrict__ f1_b,
                 const float* __restrict__ f2_W, const float* __restrict__ f2_b,
                 const int* __restrict__ edge_index,
                 float* __restrict__ out_s, float* __restrict__ out_v) {
  __shared__ float h_t[FF * HP];
  __shared__ float w_ch[KC * C3F];
  __shared__ float e_t[TE * RBFD];
  __shared__ float f1_lds[RBFD * FF];
  __shared__ int src_lds[TE], dst_lds[TE];
  __shared__ float rh_lds[TE * 3];
  __shared__ float s_t[FF * HP];

  const int tid = threadIdx.x;
  const int e0 = blockIdx.x * TE;

  if (tid < TE) {
    src_lds[tid] = edge_index[e0 + tid];
    dst_lds[tid] = edge_index[EE + e0 + tid];
  }
  if (tid < TE * 3) rh_lds[tid] = r_hat[(size_t)e0 * 3 + tid];
  for (int i = tid; i < TE * RBFD; i += 256) e_t[i] = e_ij[(size_t)e0 * RBFD + i];
  for (int i = tid; i < RBFD * FF; i += 256) f1_lds[i] = f1_W[i];
  __syncthreads();

  for (int i = tid; i < TE * FF; i += 256) {
    int e = i >> 7, f = i & 127;
    float x = f1_b[f];
#pragma unroll
    for (int k = 0; k < RBFD; ++k) x += e_t[e * RBFD + k] * f1_lds[k * FF + f];
    h_t[f * HP + e] = softplus_m_log2(x);
  }
  for (int i = tid; i < TE * (FF / 4); i += 256) {
    int e = i >> 5, k4 = i & 31;
    int d = dst_lds[e];
    float4 sv = *(const float4*)(sfeat + (size_t)d * FF + k4 * 4);
    s_t[(k4 * 4 + 0) * HP + e] = sv.x;
    s_t[(k4 * 4 + 1) * HP + e] = sv.y;
    s_t[(k4 * 4 + 2) * HP + e] = sv.z;
    s_t[(k4 * 4 + 3) * HP + e] = sv.w;
  }

  const int tc = tid & 31, tr = tid >> 5;
  float facc[3][4][4];
  float pacc[2][4][4];
#pragma unroll
  for (int g = 0; g < 3; ++g)
#pragma unroll
    for (int a = 0; a < 4; ++a)
#pragma unroll
      for (int b = 0; b < 4; ++b) facc[g][a][b] = 0.f;
#pragma unroll
  for (int g = 0; g < 2; ++g)
#pragma unroll
    for (int a = 0; a < 4; ++a)
#pragma unroll
      for (int b = 0; b < 4; ++b) pacc[g][a][b] = 0.f;

  for (int kc = 0; kc < FF / KC; ++kc) {
    __syncthreads();
    for (int i = tid; i < KC * C3F / 4; i += 256)
      *(float4*)&w_ch[i * 4] =
          *(const float4*)(f2_W + (size_t)kc * KC * C3F + i * 4);
    __syncthreads();
#pragma unroll
    for (int k = 0; k < KC; ++k) {
      float4 h4 = *(const float4*)&h_t[(kc * KC + k) * HP + tr * 4];
      float hr[4] = {h4.x, h4.y, h4.z, h4.w};
#pragma unroll
      for (int g = 0; g < 3; ++g) {
        float4 w4 = *(const float4*)&w_ch[k * C3F + g * 128 + tc * 4];
        float wr[4] = {w4.x, w4.y, w4.z, w4.w};
#pragma unroll
        for (int er = 0; er < 4; ++er)
#pragma unroll
          for (int fc = 0; fc < 4; ++fc) facc[g][er][fc] += hr[er] * wr[fc];
      }
    }
  }

  for (int kc = 0; kc < FF / KC; ++kc) {
    __syncthreads();
    for (int i = tid; i < KC * 64; i += 256) {
      int k = i >> 6, j4 = i & 63;
      int j = j4 * 4;
      int col = (j < 128) ? j : (j + 128);
      *(float4*)&w_ch[k * C3F + j] =
          *(const float4*)(phi_W + (size_t)(kc * KC + k) * C3F + col);
    }
    __syncthreads();
#pragma unroll
    for (int k = 0; k < KC; ++k) {
      float4 s4 = *(const float4*)&s_t[(kc * KC + k) * HP + tr * 4];
      float sr[4] = {s4.x, s4.y, s4.z, s4.w};
#pragma unroll
      for (int g = 0; g < 2; ++g) {
        float4 w4 = *(const float4*)&w_ch[k * C3F + g * 128 + tc * 4];
        float wr[4] = {w4.x, w4.y, w4.z, w4.w};
#pragma unroll
        for (int er = 0; er < 4; ++er)
#pragma unroll
          for (int fc = 0; fc < 4; ++fc) pacc[g][er][fc] += sr[er] * wr[fc];
      }
    }
  }

  const int f0 = tc * 4;
  float4 bs4 = *(const float4*)(f2_b + f0);
  float4 bv4 = *(const float4*)(f2_b + FF + f0);
  float4 br4 = *(const float4*)(f2_b + 2 * FF + f0);
  float bs[4] = {bs4.x, bs4.y, bs4.z, bs4.w};
  float bv[4] = {bv4.x, bv4.y, bv4.z, bv4.w};
  float br[4] = {br4.x, br4.y, br4.z, br4.w};
  float4 p0b = *(const float4*)(phi_b + f0);
  float4 p2b = *(const float4*)(phi_b + 256 + f0);
  float pb0[4] = {p0b.x, p0b.y, p0b.z, p0b.w};
  float pb2[4] = {p2b.x, p2b.y, p2b.z, p2b.w};

#pragma unroll
  for (int er = 0; er < 4; ++er) {
    const int e = tr * 4 + er;
    const int sg = src_lds[e];
    const int dg = dst_lds[e];
    const float r0c = rh_lds[e * 3 + 0];
    const float r1c = rh_lds[e * 3 + 1];
    const float r2c = rh_lds[e * 3 + 2];

    float ps[4], pr[4];
#pragma unroll
    for (int fc = 0; fc < 4; ++fc) {
      ps[fc] = pacc[0][er][fc] + pb0[fc];
      pr[fc] = pacc[1][er][fc] + pb2[fc];
    }

    float pv[12];
    const float* vp = v + ((size_t)dg * FF + f0) * 3;
    float4 v0 = *(const float4*)(vp);
    float4 v1 = *(const float4*)(vp + 4);
    float4 v2 = *(const float4*)(vp + 8);
    pv[0] = v0.x; pv[1] = v0.y; pv[2] = v0.z; pv[3] = v0.w;
    pv[4] = v1.x; pv[5] = v1.y; pv[6] = v1.z; pv[7] = v1.w;
    pv[8] = v2.x; pv[9] = v2.y; pv[10] = v2.z; pv[11] = v2.w;

    float* os = out_s + (size_t)sg * FF + f0;
    float* ov = out_v + ((size_t)sg * FF + f0) * 3;
#pragma unroll
    for (int fc = 0; fc < 4; ++fc) {
      float Ws = facc[0][er][fc] + bs[fc];
      float Wv = facc[1][er][fc] + bv[fc];
      float Wr = facc[2][er][fc] + br[fc];
      atomicAdd(os + fc, Ws * ps[fc]);
      float wrp = Wr * pr[fc];
      atomicAdd(ov + fc * 3 + 0, Wv * pv[fc * 3 + 0] + wrp * r0c);
      atomicAdd(ov + fc * 3 + 1, Wv * pv[fc * 3 + 1] + wrp * r1c);
      atomicAdd(ov + fc * 3 + 2, Wv * pv[fc * 3 + 2] + wrp * r2c);
    }
  }
}

extern "C" void kernel_launch(void* const* d_in, const int* in_sizes, int n_in,
                              void* d_out, int out_size, void* d_ws, size_t ws_size,
                              hipStream_t stream) {
  const float* s      = (const float*)d_in[0];
  const float* v      = (const float*)d_in[1];
  const float* e_ij   = (const float*)d_in[2];
  const float* r_hat  = (const float*)d_in[3];
  const float* phi_W  = (const float*)d_in[4];
  const float* phi_b  = (const float*)d_in[5];
  const float* f1_W   = (const float*)d_in[6];
  const float* f1_b   = (const float*)d_in[7];
  const float* f2_W   = (const float*)d_in[8];
  const float* f2_b   = (const float*)d_in[9];
  const int* edge_index = (const int*)d_in[10];

  float* out = (float*)d_out;
  float* out_s = out;                       // (N, F)
  float* out_v = out + (size_t)NN * FF;     // (N, F, 3)

  // ---------- NEW (huge) layout ----------
  // ints: row_start[50008] | cursor[NN] | perm[EE] | dst_perm[EE]
  // floats: rhp[EE*3]
  // shorts: phi_b16[NN*256] | f2t[384*128] | f1t[128*40] | f2frag[384*128]
  //         | v_b16[NN*384] | h_perm[EE*128]
  {
    int*   row_start = (int*)d_ws;
    int*   cursor    = row_start + 50008;
    int*   perm      = cursor + NN;
    int*   dst_perm  = perm + EE;
    float* rhp       = (float*)(dst_perm + EE);
    short* phi_b16   = (short*)(rhp + (size_t)EE * 3);
    short* f2t       = phi_b16 + (size_t)NN * 256;
    short* f1t       = f2t + C3F * FF;
    short* f2frag    = f1t + FF * 40;
    short* v_b16     = f2frag + C3F * FF;
    short* h_perm    = v_b16 + (size_t)NN * 384;
    const size_t huge_bytes =
        (size_t)(50008 + NN + EE + EE) * 4 + (size_t)EE * 3 * 4 +
        ((size_t)NN * 256 + (size_t)C3F * FF * 2 + (size_t)FF * 40 +
         (size_t)NN * 384 + (size_t)EE * FF) * 2;

    if (ws_size >= huge_bytes) {
      hipMemsetAsync(cursor, 0, (size_t)NN * sizeof(int), stream);
      hist_kernel<<<(EE + 255) / 256, 256, 0, stream>>>(edge_index, cursor);
      scan_kernel<<<1, 1024, 0, stream>>>(cursor, row_start);
      fill2_kernel<<<(EE + 255) / 256, 256, 0, stream>>>(edge_index, cursor, perm, dst_perm);
      conv_kernel<<<(C3F * FF + 255) / 256, 256, 0, stream>>>(f1_W, f2_W, f1t, f2t, f2frag);
      phi_kernel<<<(NN + TE - 1) / TE, 256, 0, stream>>>(s, phi_W, phi_b, phi_b16);
      vconv_kernel<<<(NN * 192 + 255) / 256, 256, 0, stream>>>(v, v_b16);
      h_kernel<<<(EE + TEH - 1) / TEH, 256, 0, stream>>>(e_ij, f1_b, r_hat, perm, f1t,
                                                         h_perm, rhp);
      node2_kernel<<<1024, 256, 0, stream>>>(v_b16, rhp, f2_b, row_start, dst_perm,
                                             phi_b16, h_perm, f2frag, out_s, out_v);
      return;
    }
  }

  // ---------- OLD layouts (fallback tiers, unchanged) ----------
  int* row_start = (int*)d_ws;
  int* cursor    = row_start + 50008;
  int* perm      = cursor + NN;
  short* phi_b16 = (short*)(perm + EE);
  short* f2t     = phi_b16 + (size_t)NN * 256;
  short* f1t     = f2t + C3F * FF;
  short* v_b16   = f1t + FF * 40;
  const size_t mid_bytes  = (size_t)(50008 + NN + EE) * 4 +
                            ((size_t)NN * 256 + C3F * FF + FF * 40) * 2;
  const size_t full_bytes = mid_bytes + (size_t)NN * 384 * 2;

  if (ws_size >= mid_bytes) {
    hipMemsetAsync(cursor, 0, (size_t)NN * sizeof(int), stream);
    hist_kernel<<<(EE + 255) / 256, 256, 0, stream>>>(edge_index, cursor);
    scan_kernel<<<1, 1024, 0, stream>>>(cursor, row_start);
    fill_kernel<<<(EE + 255) / 256, 256, 0, stream>>>(edge_index, cursor, perm);
    conv_kernel<<<(C3F * FF + 255) / 256, 256, 0, stream>>>(f1_W, f2_W, f1t, f2t, nullptr);
    phi_kernel<<<(NN + TE - 1) / TE, 256, 0, stream>>>(s, phi_W, phi_b, phi_b16);
    if (ws_size >= full_bytes) {
      vconv_kernel<<<(NN * 192 + 255) / 256, 256, 0, stream>>>(v, v_b16);
      node_mfma_kernel<true><<<768, 256, 0, stream>>>(
          v, v_b16, e_ij, r_hat, f1_b, f2_b, edge_index, row_start, perm,
          phi_b16, f1t, f2t, out_s, out_v);
    } else {
      node_mfma_kernel<false><<<768, 256, 0, stream>>>(
          v, nullptr, e_ij, r_hat, f1_b, f2_b, edge_index, row_start, perm,
          phi_b16, f1t, f2t, out_s, out_v);
    }
  } else {
    hipMemsetAsync(d_out, 0, (size_t)out_size * sizeof(float), stream);
    edge_kernel<<<EE / TE, 256, 0, stream>>>(
        s, v, e_ij, r_hat, phi_W, phi_b, f1_W, f1_b, f2_W, f2_b, edge_index,
        out_s, out_v);
  }
}

// Round 8
// 1193.635 us; speedup vs baseline: 1.9355x; 1.9355x over previous
//
#include <hip/hip_runtime.h>
#include <math.h>

// Problem constants (match reference)
#define NN   50000
#define FF   128
#define RBFD 20
#define EE   800000
#define C3F  384
#define TE   32      // phi tile / fallback tile
#define TN   16      // edges per chunk in node kernel (MFMA M=16)
#define TEH  64      // edges per block in h_kernel
#define KC   16      // k-chunk staged in LDS (fallback kernels)
#define HP   36      // padded stride for fallback LDS tiles

typedef __attribute__((ext_vector_type(8))) short bhalf8;   // 8 bf16 (4 VGPRs)
typedef __attribute__((ext_vector_type(4))) float floatx4;  // MFMA acc

__device__ __forceinline__ float softplus_m_log2(float x) {
  float t = __expf(-fabsf(x));
  return fmaxf(x, 0.0f) + __logf(1.0f + t) - 0.6931471805599453f;
}

__device__ __forceinline__ short f2bf(float x) {
  unsigned u = __float_as_uint(x);
  u += 0x7fffu + ((u >> 16) & 1u);   // round-to-nearest-even
  return (short)(u >> 16);
}
__device__ __forceinline__ float bflo(unsigned u) { return __uint_as_float(u << 16); }
__device__ __forceinline__ float bfhi(unsigned u) { return __uint_as_float(u & 0xffff0000u); }

// packed feature index: pairs (f, f+16) adjacent within each 32-feature group
__device__ __forceinline__ int pkf(int f) {
  return ((f >> 5) << 5) | ((f & 15) << 1) | ((f >> 4) & 1);
}

// ==================== CSR build ====================
__global__ void hist_kernel(const int* __restrict__ edge_index, int* __restrict__ cursor) {
  int e = blockIdx.x * 256 + threadIdx.x;
  if (e < EE) atomicAdd(&cursor[edge_index[e]], 1);
}

// single-block scan, each thread owns 49 consecutive elements
__global__ void scan_kernel(int* __restrict__ cursor, int* __restrict__ row_start) {
  __shared__ int sums[1024];
  const int tid = threadIdx.x;
  const int CH = 49;                 // 49*1024 >= NN
  int base = tid * CH;
  int vals[CH];
  int local = 0;
#pragma unroll
  for (int j = 0; j < CH; ++j) {
    int i = base + j;
    int x = (i < NN) ? cursor[i] : 0;
    vals[j] = x;
    local += x;
  }
  sums[tid] = local;
  __syncthreads();
  for (int off = 1; off < 1024; off <<= 1) {
    int v2 = (tid >= off) ? sums[tid - off] : 0;
    __syncthreads();
    sums[tid] += v2;
    __syncthreads();
  }
  int excl = sums[tid] - local;
#pragma unroll
  for (int j = 0; j < CH; ++j) {
    int i = base + j;
    if (i < NN) { row_start[i] = excl; cursor[i] = excl; }
    excl += vals[j];
  }
  if (tid == 1023) row_start[NN] = excl;
}

__global__ void fill_kernel(const int* __restrict__ edge_index, int* __restrict__ cursor,
                            int* __restrict__ perm) {
  int e = blockIdx.x * 256 + threadIdx.x;
  if (e < EE) {
    int s = edge_index[e];
    int pos = atomicAdd(&cursor[s], 1);
    perm[pos] = e;
  }
}

// fill that also materializes dst in permuted order (kills one gather hop)
__global__ void fill2_kernel(const int* __restrict__ edge_index, int* __restrict__ cursor,
                             int* __restrict__ perm, int* __restrict__ dst_perm) {
  int e = blockIdx.x * 256 + threadIdx.x;
  if (e < EE) {
    int s = edge_index[e];
    int d = edge_index[EE + e];
    int pos = atomicAdd(&cursor[s], 1);
    perm[pos] = e;
    dst_perm[pos] = d;
  }
}

// ==================== weight conversion: f2t[n][k]=bf16(f2_W[k][n]); f1t[f][40]
__global__ void conv_kernel(const float* __restrict__ f1_W, const float* __restrict__ f2_W,
                            short* __restrict__ f1t, short* __restrict__ f2t) {
  int i = blockIdx.x * 256 + threadIdx.x;
  if (i < C3F * FF) {
    int n = i >> 7, k = i & 127;
    f2t[i] = f2bf(f2_W[(size_t)k * C3F + n]);
  }
  if (i < FF * 40) {
    int f = i / 40, k = i - f * 40;
    f1t[i] = (k < RBFD) ? f2bf(f1_W[(size_t)k * FF + f]) : (short)0;
  }
}

// ==================== v -> packed bf16 (4B-word stores, coalesced)
// layout: v_b16[n][g*96 + l*6 + c*2 + h] shorts; one thread packs the (h=0,h=1) pair
__global__ void vconv_kernel(const float* __restrict__ v, short* __restrict__ v_b16) {
  int i = blockIdx.x * 256 + threadIdx.x;
  if (i < NN * 192) {
    int n = i / 192;
    int rem = i - n * 192;
    int g = rem / 48;
    int w = rem - g * 48;
    int l = w / 3;
    int c = w - l * 3;
    float v0 = v[((size_t)n * FF + g * 32 + l) * 3 + c];        // h=0 -> f=g*32+l
    float v1 = v[((size_t)n * FF + g * 32 + 16 + l) * 3 + c];   // h=1 -> f=g*32+16+l
    unsigned word = (unsigned)(unsigned short)f2bf(v0) |
                    ((unsigned)(unsigned short)f2bf(v1) << 16);
    ((unsigned*)v_b16)[(size_t)n * 192 + rem] = word;
  }
}

// ==================== per-node phi GEMM -> packed bf16 phi_b16[n][256]
// [0:128] = phi_s+b (pkf layout), [128:256] = phi_r+b
__global__ __launch_bounds__(256, 3)
void phi_kernel(const float* __restrict__ s, const float* __restrict__ phi_W,
                const float* __restrict__ phi_b, short* __restrict__ phi_b16) {
  __shared__ float s_t[FF * HP];
  __shared__ __align__(16) float w_ch[KC * 256];   // reused as output staging
  const int tid = threadIdx.x;
  const int r0 = blockIdx.x * TE;

  for (int i = tid; i < TE * (FF / 4); i += 256) {
    int row = i >> 5, k4 = i & 31;
    int rg = r0 + row;
    float4 sv = make_float4(0.f, 0.f, 0.f, 0.f);
    if (rg < NN) sv = *(const float4*)(s + (size_t)rg * FF + k4 * 4);
    s_t[(k4 * 4 + 0) * HP + row] = sv.x;
    s_t[(k4 * 4 + 1) * HP + row] = sv.y;
    s_t[(k4 * 4 + 2) * HP + row] = sv.z;
    s_t[(k4 * 4 + 3) * HP + row] = sv.w;
  }
  const int tc = tid & 31, tr = tid >> 5;
  float acc[2][4][4];
#pragma unroll
  for (int g = 0; g < 2; ++g)
#pragma unroll
    for (int a = 0; a < 4; ++a)
#pragma unroll
      for (int b = 0; b < 4; ++b) acc[g][a][b] = 0.f;

  for (int kc = 0; kc < FF / KC; ++kc) {
    __syncthreads();
    for (int i = tid; i < KC * 64; i += 256) {
      int k = i >> 6, j4 = i & 63;
      int j = j4 * 4;
      int col = (j < 128) ? j : (j + 128);
      *(float4*)&w_ch[k * 256 + j] =
          *(const float4*)(phi_W + (size_t)(kc * KC + k) * C3F + col);
    }
    __syncthreads();
#pragma unroll
    for (int k = 0; k < KC; ++k) {
      float4 s4 = *(const float4*)&s_t[(kc * KC + k) * HP + tr * 4];
      float sr[4] = {s4.x, s4.y, s4.z, s4.w};
#pragma unroll
      for (int g = 0; g < 2; ++g) {
        float4 w4 = *(const float4*)&w_ch[k * 256 + g * 128 + tc * 4];
        float wr[4] = {w4.x, w4.y, w4.z, w4.w};
#pragma unroll
        for (int er = 0; er < 4; ++er)
#pragma unroll
          for (int fc = 0; fc < 4; ++fc) acc[g][er][fc] += sr[er] * wr[fc];
      }
    }
  }
  const int f0 = tc * 4;
  float4 b0 = *(const float4*)(phi_b + f0);
  float4 b2 = *(const float4*)(phi_b + 256 + f0);
  float bb[2][4] = {{b0.x, b0.y, b0.z, b0.w}, {b2.x, b2.y, b2.z, b2.w}};

  __syncthreads();                       // done reading w_ch as weights
  short* ob = (short*)w_ch;              // [32 rows][256] packed bf16
#pragma unroll
  for (int er = 0; er < 4; ++er) {
    int row = tr * 4 + er;
#pragma unroll
    for (int g = 0; g < 2; ++g) {
#pragma unroll
      for (int fc = 0; fc < 4; ++fc) {
        int f = f0 + fc;
        ob[row * 256 + g * 128 + pkf(f)] = f2bf(acc[g][er][fc] + bb[g][fc]);
      }
    }
  }
  __syncthreads();
  // coalesced store: 32 rows x 512B = 1024 int4
  for (int i = tid; i < 1024; i += 256) {
    int row = i >> 5;
    int rg = r0 + row;
    if (rg < NN)
      ((int4*)(phi_b16 + (size_t)rg * 256))[i & 31] = ((const int4*)ob)[i];
  }
}

// ==================== edge-parallel h precompute in permuted order ====================
// h_perm[i][f] = bf16( softplus(e_ij[perm[i]] @ f1_W + f1_b) - log2 ), plain f order
// ALSO writes rhp (r_hat in permuted order, stride 3) -- folded-in rperm.
__global__ __launch_bounds__(256, 6)
void h_kernel(const float* __restrict__ e_ij, const float* __restrict__ f1_b,
              const float* __restrict__ r_hat,
              const int* __restrict__ perm, const short* __restrict__ f1t_g,
              short* __restrict__ h_perm, float* __restrict__ rhp) {
  __shared__ __align__(16) short e_pad2[TEH * 40];  // 5 KB
  __shared__ int pl[TEH];
  const int tid = threadIdx.x;
  const int wid = tid >> 6;
  const int lane = tid & 63;
  const int l = lane & 15;
  const int q = lane >> 4;
  const int e0 = blockIdx.x * TEH;

  if (tid < TEH) {
    int idx = e0 + tid;
    pl[tid] = (idx < EE) ? perm[idx] : -1;
  }
  __syncthreads();
  // r_hat permute (gathered read, coalesced write)
  if (tid < TEH * 3) {
    int le = tid / 3, c = tid - le * 3;
    int idx = e0 + le;
    if (idx < EE) {
      int eid = pl[le];
      rhp[(size_t)idx * 3 + c] = (eid >= 0) ? r_hat[(size_t)eid * 3 + c] : 0.f;
    }
  }
  for (int i = tid; i < TEH * 32; i += 256) {
    int e = i >> 5, k = i & 31;
    int eid = pl[e];
    float val = (eid >= 0 && k < RBFD) ? e_ij[(size_t)eid * RBFD + k] : 0.f;
    e_pad2[e * 40 + k] = f2bf(val);
  }
  const int f0 = wid * 32 + l;
  const int f1 = f0 + 16;
  const bhalf8 b1f0 = *(const bhalf8*)(f1t_g + f0 * 40 + q * 8);
  const bhalf8 b1f1 = *(const bhalf8*)(f1t_g + f1 * 40 + q * 8);
  const float f1b0 = f1_b[f0], f1b1 = f1_b[f1];
  __syncthreads();

#pragma unroll
  for (int rt = 0; rt < 4; ++rt) {
    bhalf8 a = *(const bhalf8*)(&e_pad2[(rt * 16 + l) * 40 + q * 8]);
    floatx4 h0 = {0.f, 0.f, 0.f, 0.f}, h1 = {0.f, 0.f, 0.f, 0.f};
    h0 = __builtin_amdgcn_mfma_f32_16x16x32_bf16(a, b1f0, h0, 0, 0, 0);
    h1 = __builtin_amdgcn_mfma_f32_16x16x32_bf16(a, b1f1, h1, 0, 0, 0);
#pragma unroll
    for (int r = 0; r < 4; ++r) {
      int idx = e0 + rt * 16 + q * 4 + r;
      if (idx < EE) {
        h_perm[(size_t)idx * FF + f0] = f2bf(softplus_m_log2(h0[r] + f1b0));
        h_perm[(size_t)idx * FF + f1] = f2bf(softplus_m_log2(h1[r] + f1b1));
      }
    }
  }
}

// ==================== barrier-free, LDS-free node kernel (persistent) ==================
// VERBATIM round-1-bench version: (256,3), grid 768, Bfr held, dst loaded inside
// chunk, rh in epilogue. 655us, VGPR 84, no spill, PASSED. R6/R7 lesson: at the
// 170-total-reg budget of bounds-3, adding live state (dgN prefetch + hoisted rh)
// correlates with delta_v corruption -- do not stack unverified deltas here.
__global__ __launch_bounds__(256, 3)
void node2_kernel(const short* __restrict__ v_b16, const float* __restrict__ rhp,
                  const float* __restrict__ f2_b,
                  const int* __restrict__ row_start, const int* __restrict__ dst_perm,
                  const short* __restrict__ phi_b16, const short* __restrict__ h_perm,
                  const short* __restrict__ f2t_g,
                  float* __restrict__ out_s, float* __restrict__ out_v) {
  const int tid = threadIdx.x;
  const int wid = tid >> 6;
  const int lane = tid & 63;
  const int l = lane & 15;
  const int q = lane >> 4;
  const int f0 = wid * 32 + l;
  const int f1 = f0 + 16;

  const float bs0 = f2_b[f0],        bs1 = f2_b[f1];
  const float bv0 = f2_b[FF + f0],   bv1 = f2_b[FF + f1];
  const float br0 = f2_b[2*FF + f0], br1 = f2_b[2*FF + f1];

  // filt-GEMM B fragments (L2-resident f2t; loaded once per block, held)
  bhalf8 Bfr[6][4];
#pragma unroll
  for (int j = 0; j < 6; ++j) {
    int g = j >> 1, hh = j & 1;
    int nc = g * 128 + wid * 32 + hh * 16 + l;
#pragma unroll
    for (int ks = 0; ks < 4; ++ks)
      Bfr[j][ks] = *(const bhalf8*)(f2t_g + (size_t)nc * FF + ks * 32 + q * 8);
  }

  for (int n = blockIdx.x; n < NN; n += gridDim.x) {
    const int rs = row_start[n];
    const int deg = row_start[n + 1] - rs;

    float dsA[2] = {0.f, 0.f};
    float dvA[2][3] = {{0.f, 0.f, 0.f}, {0.f, 0.f, 0.f}};

    for (int c0 = 0; c0 < deg; c0 += TN) {
      const int cnt = min(TN, deg - c0);
      const int base = rs + c0;

      // ---- dst for this lane's 4 output rows (broadcast loads, streamed array)
      int dg[4];
#pragma unroll
      for (int r = 0; r < 4; ++r) {
        int idx = min(base + q * 4 + r, EE - 1);   // clamp: garbage rows masked later
        dg[r] = dst_perm[idx];
      }

      // ---- issue phi/v gathers EARLY so they fly under the MFMA block
      unsigned psu[4], pru[4], vu0[4], vu1[4], vu2[4];
#pragma unroll
      for (int r = 0; r < 4; ++r) {
        const short* pb = phi_b16 + (size_t)dg[r] * 256 + wid * 32 + l * 2;
        psu[r] = *(const unsigned*)pb;
        pru[r] = *(const unsigned*)(pb + 128);
        const short* vb = v_b16 + (size_t)dg[r] * 384 + wid * 96 + l * 6;
        vu0[r] = ((const unsigned*)vb)[0];
        vu1[r] = ((const unsigned*)vb)[1];
        vu2[r] = ((const unsigned*)vb)[2];
      }

      // ---- filt-GEMM: K=128, A straight from h_perm (contiguous rows), B resident
      const int hrow = min(base + l, EE - 1);
      const short* hp = h_perm + (size_t)hrow * FF + q * 8;
      floatx4 acc[6];
#pragma unroll
      for (int j = 0; j < 6; ++j) acc[j] = (floatx4){0.f, 0.f, 0.f, 0.f};
#pragma unroll
      for (int ks = 0; ks < 4; ++ks) {
        bhalf8 a = *(const bhalf8*)(hp + ks * 32);
#pragma unroll
        for (int j = 0; j < 6; ++j)
          acc[j] = __builtin_amdgcn_mfma_f32_16x16x32_bf16(a, Bfr[j][ks], acc[j], 0, 0, 0);
      }

      // ---- epilogue: branchless masked accumulate (gathers already in registers)
#pragma unroll
      for (int r = 0; r < 4; ++r) {
        int e = q * 4 + r;
        float valid = (e < cnt) ? 1.0f : 0.0f;
        float Ws0 = (acc[0][r] + bs0) * valid, Ws1 = (acc[1][r] + bs1) * valid;
        float Wv0 = (acc[2][r] + bv0) * valid, Wv1 = (acc[3][r] + bv1) * valid;
        float Wr0 = (acc[4][r] + br0) * valid, Wr1 = (acc[5][r] + br1) * valid;

        float ps0 = bflo(psu[r]), ps1 = bfhi(psu[r]);
        float pr0 = bflo(pru[r]), pr1 = bfhi(pru[r]);
        float v00 = bflo(vu0[r]), v10 = bfhi(vu0[r]);
        float v01 = bflo(vu1[r]), v11 = bfhi(vu1[r]);
        float v02 = bflo(vu2[r]), v12 = bfhi(vu2[r]);

        int ridx = min(base + e, EE - 1);
        const float* rp = rhp + (size_t)ridx * 3;
        float rh0 = rp[0], rh1 = rp[1], rh2 = rp[2];

        dsA[0] += Ws0 * ps0;
        dsA[1] += Ws1 * ps1;
        float w0 = Wr0 * pr0, w1 = Wr1 * pr1;
        dvA[0][0] += Wv0 * v00 + w0 * rh0;
        dvA[0][1] += Wv0 * v01 + w0 * rh1;
        dvA[0][2] += Wv0 * v02 + w0 * rh2;
        dvA[1][0] += Wv1 * v10 + w1 * rh0;
        dvA[1][1] += Wv1 * v11 + w1 * rh1;
        dvA[1][2] += Wv1 * v12 + w1 * rh2;
      }
    }

    // quad reduction (within wave)
#pragma unroll
    for (int a = 0; a < 2; ++a) {
      dsA[a] += __shfl_xor(dsA[a], 16);
      dsA[a] += __shfl_xor(dsA[a], 32);
#pragma unroll
      for (int c = 0; c < 3; ++c) {
        dvA[a][c] += __shfl_xor(dvA[a][c], 16);
        dvA[a][c] += __shfl_xor(dvA[a][c], 32);
      }
    }

    // direct stores from q==0 lanes (no LDS staging, no barriers)
    if (q == 0) {
      out_s[(size_t)n * FF + f0] = dsA[0];
      out_s[(size_t)n * FF + f1] = dsA[1];
#pragma unroll
      for (int c = 0; c < 3; ++c) {
        out_v[((size_t)n * FF + f0) * 3 + c] = dvA[0][c];
        out_v[((size_t)n * FF + f1) * 3 + c] = dvA[1][c];
      }
    }
  }
}

// ==================== OLD node-centric MFMA kernel (fallback tier) ====================
template <bool VB16>
__global__ __launch_bounds__(256, 3)
void node_mfma_kernel(const float* __restrict__ vf32, const short* __restrict__ v_b16,
                      const float* __restrict__ e_ij, const float* __restrict__ r_hat,
                      const float* __restrict__ f1_b, const float* __restrict__ f2_b,
                      const int* __restrict__ edge_index,
                      const int* __restrict__ row_start, const int* __restrict__ perm,
                      const short* __restrict__ phi_b16,
                      const short* __restrict__ f1t_g, const short* __restrict__ f2t_g,
                      float* __restrict__ out_s, float* __restrict__ out_v) {
  __shared__ __align__(16) short f1t_l[FF * 40];   // 10 KB
  __shared__ __align__(16) short e_pad[TN * 40];   // 1.25 KB
  __shared__ __align__(16) short h_buf[TN * 136];  // 4.25 KB; reused as f32 out staging
  __shared__ float rh_l[TN * 3];
  __shared__ int el[TN], dl[TN];

  const int tid = threadIdx.x;
  const int wid = tid >> 6;
  const int lane = tid & 63;
  const int l = lane & 15;
  const int q = lane >> 4;

  for (int i = tid; i < FF * 40 / 2; i += 256)
    ((int*)f1t_l)[i] = ((const int*)f1t_g)[i];

  const int f0 = wid * 32 + l;
  const int f1 = f0 + 16;

  const float f1b0 = f1_b[f0], f1b1 = f1_b[f1];
  const float bs0 = f2_b[f0],        bs1 = f2_b[f1];
  const float bv0 = f2_b[FF + f0],   bv1 = f2_b[FF + f1];
  const float br0 = f2_b[2*FF + f0], br1 = f2_b[2*FF + f1];

  bhalf8 Bfr[6][4];
#pragma unroll
  for (int j = 0; j < 6; ++j) {
    int g = j >> 1, hh = j & 1;
    int nc = g * 128 + wid * 32 + hh * 16 + l;
#pragma unroll
    for (int ks = 0; ks < 4; ++ks)
      Bfr[j][ks] = *(const bhalf8*)(f2t_g + (size_t)nc * FF + ks * 32 + q * 8);
  }

  __syncthreads();
  const bhalf8 b1f0 = *(const bhalf8*)(&f1t_l[f0 * 40 + q * 8]);
  const bhalf8 b1f1 = *(const bhalf8*)(&f1t_l[f1 * 40 + q * 8]);

  for (int n = blockIdx.x; n < NN; n += gridDim.x) {
    const int rs = row_start[n];
    const int deg = row_start[n + 1] - rs;

    float dsA[2] = {0.f, 0.f};
    float dvA[2][3] = {{0.f, 0.f, 0.f}, {0.f, 0.f, 0.f}};

    for (int c0 = 0; c0 < deg; c0 += TN) {
      const int cnt = min(TN, deg - c0);
      __syncthreads();

      if (tid < TN) {
        int idx = c0 + tid;
        int eid = (idx < deg) ? perm[rs + idx] : -1;
        el[tid] = eid;
        dl[tid] = (eid >= 0) ? edge_index[EE + eid] : 0;
        if (eid >= 0) {
          rh_l[tid * 3 + 0] = r_hat[(size_t)eid * 3 + 0];
          rh_l[tid * 3 + 1] = r_hat[(size_t)eid * 3 + 1];
          rh_l[tid * 3 + 2] = r_hat[(size_t)eid * 3 + 2];
        } else {
          rh_l[tid * 3 + 0] = 0.f; rh_l[tid * 3 + 1] = 0.f; rh_l[tid * 3 + 2] = 0.f;
        }
      }
      __syncthreads();
      for (int i = tid; i < TN * 32; i += 256) {
        int e = i >> 5, k = i & 31;
        int eid = el[e];
        float val = (eid >= 0 && k < RBFD) ? e_ij[(size_t)eid * RBFD + k] : 0.f;
        e_pad[e * 40 + k] = f2bf(val);
      }
      __syncthreads();

      {
        bhalf8 a = *(const bhalf8*)(&e_pad[l * 40 + q * 8]);
        floatx4 h0 = {0.f, 0.f, 0.f, 0.f}, h1 = {0.f, 0.f, 0.f, 0.f};
        h0 = __builtin_amdgcn_mfma_f32_16x16x32_bf16(a, b1f0, h0, 0, 0, 0);
        h1 = __builtin_amdgcn_mfma_f32_16x16x32_bf16(a, b1f1, h1, 0, 0, 0);
#pragma unroll
        for (int r = 0; r < 4; ++r) {
          int e = q * 4 + r;
          h_buf[e * 136 + f0] = f2bf(softplus_m_log2(h0[r] + f1b0));
          h_buf[e * 136 + f1] = f2bf(softplus_m_log2(h1[r] + f1b1));
        }
      }
      __syncthreads();

      floatx4 acc[6];
#pragma unroll
      for (int j = 0; j < 6; ++j) acc[j] = (floatx4){0.f, 0.f, 0.f, 0.f};
#pragma unroll
      for (int ks = 0; ks < 4; ++ks) {
        bhalf8 a = *(const bhalf8*)(&h_buf[l * 136 + ks * 32 + q * 8]);
#pragma unroll
        for (int j = 0; j < 6; ++j)
          acc[j] = __builtin_amdgcn_mfma_f32_16x16x32_bf16(a, Bfr[j][ks], acc[j], 0, 0, 0);
      }

#pragma unroll
      for (int r = 0; r < 4; ++r) {
        int e = q * 4 + r;
        int dg = dl[e];
        float valid = (e < cnt) ? 1.0f : 0.0f;
        float Ws0 = (acc[0][r] + bs0) * valid, Ws1 = (acc[1][r] + bs1) * valid;
        float Wv0 = (acc[2][r] + bv0) * valid, Wv1 = (acc[3][r] + bv1) * valid;
        float Wr0 = (acc[4][r] + br0) * valid, Wr1 = (acc[5][r] + br1) * valid;

        const short* pb = phi_b16 + (size_t)dg * 256 + wid * 32 + l * 2;
        unsigned psu = *(const unsigned*)pb;
        unsigned pru = *(const unsigned*)(pb + 128);
        float ps0 = bflo(psu), ps1 = bfhi(psu);
        float pr0 = bflo(pru), pr1 = bfhi(pru);

        float v00, v01, v02, v10, v11, v12;
        if constexpr (VB16) {
          const short* vb = v_b16 + (size_t)dg * 384 + wid * 96 + l * 6;
          unsigned u0 = ((const unsigned*)vb)[0];
          unsigned u1 = ((const unsigned*)vb)[1];
          unsigned u2 = ((const unsigned*)vb)[2];
          v00 = bflo(u0); v10 = bfhi(u0);
          v01 = bflo(u1); v11 = bfhi(u1);
          v02 = bflo(u2); v12 = bfhi(u2);
        } else {
          const float* vp0 = vf32 + ((size_t)dg * FF + f0) * 3;
          const float* vp1 = vf32 + ((size_t)dg * FF + f1) * 3;
          v00 = vp0[0]; v01 = vp0[1]; v02 = vp0[2];
          v10 = vp1[0]; v11 = vp1[1]; v12 = vp1[2];
        }
        float rh0 = rh_l[e * 3 + 0], rh1 = rh_l[e * 3 + 1], rh2 = rh_l[e * 3 + 2];
        dsA[0] += Ws0 * ps0;
        dsA[1] += Ws1 * ps1;
        float w0 = Wr0 * pr0, w1 = Wr1 * pr1;
        dvA[0][0] += Wv0 * v00 + w0 * rh0;
        dvA[0][1] += Wv0 * v01 + w0 * rh1;
        dvA[0][2] += Wv0 * v02 + w0 * rh2;
        dvA[1][0] += Wv1 * v10 + w1 * rh0;
        dvA[1][1] += Wv1 * v11 + w1 * rh1;
        dvA[1][2] += Wv1 * v12 + w1 * rh2;
      }
    }

#pragma unroll
    for (int a = 0; a < 2; ++a) {
      dsA[a] += __shfl_xor(dsA[a], 16);
      dsA[a] += __shfl_xor(dsA[a], 32);
#pragma unroll
      for (int c = 0; c < 3; ++c) {
        dvA[a][c] += __shfl_xor(dvA[a][c], 16);
        dvA[a][c] += __shfl_xor(dvA[a][c], 32);
      }
    }

    __syncthreads();
    float* ob = (float*)h_buf;
    if (q == 0) {
      ob[f0] = dsA[0];
      ob[f1] = dsA[1];
#pragma unroll
      for (int c = 0; c < 3; ++c) {
        ob[128 + f0 * 3 + c] = dvA[0][c];
        ob[128 + f1 * 3 + c] = dvA[1][c];
      }
    }
    __syncthreads();
    if (tid < 32)
      ((float4*)(out_s + (size_t)n * FF))[tid] = ((const float4*)ob)[tid];
    else if (tid < 128)
      ((float4*)(out_v + (size_t)n * C3F))[tid - 32] = ((const float4*)ob)[tid];
  }
}

// ==================== fallback: edge-parallel, inline phi, atomics (no ws) ============
__global__ __launch_bounds__(256, 2)
void edge_kernel(const float* __restrict__ sfeat, const float* __restrict__ v,
                 const float* __restrict__ e_ij, const float* __restrict__ r_hat,
                 const float* __restrict__ phi_W, const float* __restrict__ phi_b,
                 const float* __restrict__ f1_W, const float* __restrict__ f1_b,
                 const float* __restrict__ f2_W, const float* __restrict__ f2_b,
                 const int* __restrict__ edge_index,
                 float* __restrict__ out_s, float* __restrict__ out_v) {
  __shared__ float h_t[FF * HP];
  __shared__ float w_ch[KC * C3F];
  __shared__ float e_t[TE * RBFD];
  __shared__ float f1_lds[RBFD * FF];
  __shared__ int src_lds[TE], dst_lds[TE];
  __shared__ float rh_lds[TE * 3];
  __shared__ float s_t[FF * HP];

  const int tid = threadIdx.x;
  const int e0 = blockIdx.x * TE;

  if (tid < TE) {
    src_lds[tid] = edge_index[e0 + tid];
    dst_lds[tid] = edge_index[EE + e0 + tid];
  }
  if (tid < TE * 3) rh_lds[tid] = r_hat[(size_t)e0 * 3 + tid];
  for (int i = tid; i < TE * RBFD; i += 256) e_t[i] = e_ij[(size_t)e0 * RBFD + i];
  for (int i = tid; i < RBFD * FF; i += 256) f1_lds[i] = f1_W[i];
  __syncthreads();

  for (int i = tid; i < TE * FF; i += 256) {
    int e = i >> 7, f = i & 127;
    float x = f1_b[f];
#pragma unroll
    for (int k = 0; k < RBFD; ++k) x += e_t[e * RBFD + k] * f1_lds[k * FF + f];
    h_t[f * HP + e] = softplus_m_log2(x);
  }
  for (int i = tid; i < TE * (FF / 4); i += 256) {
    int e = i >> 5, k4 = i & 31;
    int d = dst_lds[e];
    float4 sv = *(const float4*)(sfeat + (size_t)d * FF + k4 * 4);
    s_t[(k4 * 4 + 0) * HP + e] = sv.x;
    s_t[(k4 * 4 + 1) * HP + e] = sv.y;
    s_t[(k4 * 4 + 2) * HP + e] = sv.z;
    s_t[(k4 * 4 + 3) * HP + e] = sv.w;
  }

  const int tc = tid & 31, tr = tid >> 5;
  float facc[3][4][4];
  float pacc[2][4][4];
#pragma unroll
  for (int g = 0; g < 3; ++g)
#pragma unroll
    for (int a = 0; a < 4; ++a)
#pragma unroll
      for (int b = 0; b < 4; ++b) facc[g][a][b] = 0.f;
#pragma unroll
  for (int g = 0; g < 2; ++g)
#pragma unroll
    for (int a = 0; a < 4; ++a)
#pragma unroll
      for (int b = 0; b < 4; ++b) pacc[g][a][b] = 0.f;

  for (int kc = 0; kc < FF / KC; ++kc) {
    __syncthreads();
    for (int i = tid; i < KC * C3F / 4; i += 256)
      *(float4*)&w_ch[i * 4] =
          *(const float4*)(f2_W + (size_t)kc * KC * C3F + i * 4);
    __syncthreads();
#pragma unroll
    for (int k = 0; k < KC; ++k) {
      float4 h4 = *(const float4*)&h_t[(kc * KC + k) * HP + tr * 4];
      float hr[4] = {h4.x, h4.y, h4.z, h4.w};
#pragma unroll
      for (int g = 0; g < 3; ++g) {
        float4 w4 = *(const float4*)&w_ch[k * C3F + g * 128 + tc * 4];
        float wr[4] = {w4.x, w4.y, w4.z, w4.w};
#pragma unroll
        for (int er = 0; er < 4; ++er)
#pragma unroll
          for (int fc = 0; fc < 4; ++fc) facc[g][er][fc] += hr[er] * wr[fc];
      }
    }
  }

  for (int kc = 0; kc < FF / KC; ++kc) {
    __syncthreads();
    for (int i = tid; i < KC * 64; i += 256) {
      int k = i >> 6, j4 = i & 63;
      int j = j4 * 4;
      int col = (j < 128) ? j : (j + 128);
      *(float4*)&w_ch[k * C3F + j] =
          *(const float4*)(phi_W + (size_t)(kc * KC + k) * C3F + col);
    }
    __syncthreads();
#pragma unroll
    for (int k = 0; k < KC; ++k) {
      float4 s4 = *(const float4*)&s_t[(kc * KC + k) * HP + tr * 4];
      float sr[4] = {s4.x, s4.y, s4.z, s4.w};
#pragma unroll
      for (int g = 0; g < 2; ++g) {
        float4 w4 = *(const float4*)&w_ch[k * C3F + g * 128 + tc * 4];
        float wr[4] = {w4.x, w4.y, w4.z, w4.w};
#pragma unroll
        for (int er = 0; er < 4; ++er)
#pragma unroll
          for (int fc = 0; fc < 4; ++fc) pacc[g][er][fc] += sr[er] * wr[fc];
      }
    }
  }

  const int f0 = tc * 4;
  float4 bs4 = *(const float4*)(f2_b + f0);
  float4 bv4 = *(const float4*)(f2_b + FF + f0);
  float4 br4 = *(const float4*)(f2_b + 2 * FF + f0);
  float bs[4] = {bs4.x, bs4.y, bs4.z, bs4.w};
  float bv[4] = {bv4.x, bv4.y, bv4.z, bv4.w};
  float br[4] = {br4.x, br4.y, br4.z, br4.w};
  float4 p0b = *(const float4*)(phi_b + f0);
  float4 p2b = *(const float4*)(phi_b + 256 + f0);
  float pb0[4] = {p0b.x, p0b.y, p0b.z, p0b.w};
  float pb2[4] = {p2b.x, p2b.y, p2b.z, p2b.w};

#pragma unroll
  for (int er = 0; er < 4; ++er) {
    const int e = tr * 4 + er;
    const int sg = src_lds[e];
    const int dg = dst_lds[e];
    const float r0c = rh_lds[e * 3 + 0];
    const float r1c = rh_lds[e * 3 + 1];
    const float r2c = rh_lds[e * 3 + 2];

    float ps[4], pr[4];
#pragma unroll
    for (int fc = 0; fc < 4; ++fc) {
      ps[fc] = pacc[0][er][fc] + pb0[fc];
      pr[fc] = pacc[1][er][fc] + pb2[fc];
    }

    float pv[12];
    const float* vp = v + ((size_t)dg * FF + f0) * 3;
    float4 v0 = *(const float4*)(vp);
    float4 v1 = *(const float4*)(vp + 4);
    float4 v2 = *(const float4*)(vp + 8);
    pv[0] = v0.x; pv[1] = v0.y; pv[2] = v0.z; pv[3] = v0.w;
    pv[4] = v1.x; pv[5] = v1.y; pv[6] = v1.z; pv[7] = v1.w;
    pv[8] = v2.x; pv[9] = v2.y; pv[10] = v2.z; pv[11] = v2.w;

    float* os = out_s + (size_t)sg * FF + f0;
    float* ov = out_v + ((size_t)sg * FF + f0) * 3;
#pragma unroll
    for (int fc = 0; fc < 4; ++fc) {
      float Ws = facc[0][er][fc] + bs[fc];
      float Wv = facc[1][er][fc] + bv[fc];
      float Wr = facc[2][er][fc] + br[fc];
      atomicAdd(os + fc, Ws * ps[fc]);
      float wrp = Wr * pr[fc];
      atomicAdd(ov + fc * 3 + 0, Wv * pv[fc * 3 + 0] + wrp * r0c);
      atomicAdd(ov + fc * 3 + 1, Wv * pv[fc * 3 + 1] + wrp * r1c);
      atomicAdd(ov + fc * 3 + 2, Wv * pv[fc * 3 + 2] + wrp * r2c);
    }
  }
}

extern "C" void kernel_launch(void* const* d_in, const int* in_sizes, int n_in,
                              void* d_out, int out_size, void* d_ws, size_t ws_size,
                              hipStream_t stream) {
  const float* s      = (const float*)d_in[0];
  const float* v      = (const float*)d_in[1];
  const float* e_ij   = (const float*)d_in[2];
  const float* r_hat  = (const float*)d_in[3];
  const float* phi_W  = (const float*)d_in[4];
  const float* phi_b  = (const float*)d_in[5];
  const float* f1_W   = (const float*)d_in[6];
  const float* f1_b   = (const float*)d_in[7];
  const float* f2_W   = (const float*)d_in[8];
  const float* f2_b   = (const float*)d_in[9];
  const int* edge_index = (const int*)d_in[10];

  float* out = (float*)d_out;
  float* out_s = out;                       // (N, F)
  float* out_v = out + (size_t)NN * FF;     // (N, F, 3)

  // ---------- huge layout (verified R2-R5) ----------
  // ints: row_start[50008] | cursor[NN] | perm[EE] | dst_perm[EE]
  // floats: rhp[EE*3]
  // shorts: phi_b16[NN*256] | f2t[384*128] | f1t[128*40] | v_b16[NN*384] | h_perm[EE*128]
  {
    int*   row_start = (int*)d_ws;
    int*   cursor    = row_start + 50008;
    int*   perm      = cursor + NN;
    int*   dst_perm  = perm + EE;
    float* rhp       = (float*)(dst_perm + EE);
    short* phi_b16   = (short*)(rhp + (size_t)EE * 3);
    short* f2t       = phi_b16 + (size_t)NN * 256;
    short* f1t       = f2t + C3F * FF;
    short* v_b16     = f1t + FF * 40;
    short* h_perm    = v_b16 + (size_t)NN * 384;
    const size_t huge_bytes =
        (size_t)(50008 + NN + EE + EE) * 4 + (size_t)EE * 3 * 4 +
        ((size_t)NN * 256 + (size_t)C3F * FF + (size_t)FF * 40 +
         (size_t)NN * 384 + (size_t)EE * FF) * 2;

    if (ws_size >= huge_bytes) {
      hipMemsetAsync(cursor, 0, (size_t)NN * sizeof(int), stream);
      hist_kernel<<<(EE + 255) / 256, 256, 0, stream>>>(edge_index, cursor);
      scan_kernel<<<1, 1024, 0, stream>>>(cursor, row_start);
      fill2_kernel<<<(EE + 255) / 256, 256, 0, stream>>>(edge_index, cursor, perm, dst_perm);
      conv_kernel<<<(C3F * FF + 255) / 256, 256, 0, stream>>>(f1_W, f2_W, f1t, f2t);
      phi_kernel<<<(NN + TE - 1) / TE, 256, 0, stream>>>(s, phi_W, phi_b, phi_b16);
      vconv_kernel<<<(NN * 192 + 255) / 256, 256, 0, stream>>>(v, v_b16);
      h_kernel<<<(EE + TEH - 1) / TEH, 256, 0, stream>>>(e_ij, f1_b, r_hat, perm, f1t,
                                                         h_perm, rhp);
      node2_kernel<<<768, 256, 0, stream>>>(v_b16, rhp, f2_b, row_start, dst_perm,
                                            phi_b16, h_perm, f2t, out_s, out_v);
      return;
    }
  }

  // ---------- fallback tiers ----------
  int* row_start = (int*)d_ws;
  int* cursor    = row_start + 50008;
  int* perm      = cursor + NN;
  short* phi_b16 = (short*)(perm + EE);
  short* f2t     = phi_b16 + (size_t)NN * 256;
  short* f1t     = f2t + C3F * FF;
  short* v_b16   = f1t + FF * 40;
  const size_t mid_bytes  = (size_t)(50008 + NN + EE) * 4 +
                            ((size_t)NN * 256 + C3F * FF + FF * 40) * 2;
  const size_t full_bytes = mid_bytes + (size_t)NN * 384 * 2;

  if (ws_size >= mid_bytes) {
    hipMemsetAsync(cursor, 0, (size_t)NN * sizeof(int), stream);
    hist_kernel<<<(EE + 255) / 256, 256, 0, stream>>>(edge_index, cursor);
    scan_kernel<<<1, 1024, 0, stream>>>(cursor, row_start);
    fill_kernel<<<(EE + 255) / 256, 256, 0, stream>>>(edge_index, cursor, perm);
    conv_kernel<<<(C3F * FF + 255) / 256, 256, 0, stream>>>(f1_W, f2_W, f1t, f2t);
    phi_kernel<<<(NN + TE - 1) / TE, 256, 0, stream>>>(s, phi_W, phi_b, phi_b16);
    if (ws_size >= full_bytes) {
      vconv_kernel<<<(NN * 192 + 255) / 256, 256, 0, stream>>>(v, v_b16);
      node_mfma_kernel<true><<<768, 256, 0, stream>>>(
          v, v_b16, e_ij, r_hat, f1_b, f2_b, edge_index, row_start, perm,
          phi_b16, f1t, f2t, out_s, out_v);
    } else {
      node_mfma_kernel<false><<<768, 256, 0, stream>>>(
          v, nullptr, e_ij, r_hat, f1_b, f2_b, edge_index, row_start, perm,
          phi_b16, f1t, f2t, out_s, out_v);
    }
  } else {
    hipMemsetAsync(d_out, 0, (size_t)out_size * sizeof(float), stream);
    edge_kernel<<<EE / TE, 256, 0, stream>>>(
        s, v, e_ij, r_hat, phi_W, phi_b, f1_W, f1_b, f2_W, f2_b, edge_index,
        out_s, out_v);
  }
}